// Round 15
// baseline (328.271 us; speedup 1.0000x reference)
//
#include <hip/hip_runtime.h>
#include <math.h>

#define NB 8192
#define NC 1024

#define NT   2464
#define NTR  2461
#define C0   48
#define BMAXF 1984.0f
#define UBIAS 978.5f

constexpr int OFFK[16] = {0, 69, 109, 139, 164, 187, 208, 228,
                          248, 268, 289, 312, 337, 367, 407, 476};

// ws: [16..1039] PART (real), [1040..2063] PART2 (dead diagnostics)
#define PART  16
#define PART2 1040
#define NBLK  1024

__device__ __forceinline__ float log_ndtr_f(float x) {
    float e = erfcf(-x * 0.70710678118654752f);
    if (e > 1e-37f) return __logf(0.5f * e);
    return -0.5f * x * x - 0.91893853320467274f - __logf(-x);
}

__device__ __forceinline__ float row_prob(float4 a0, float4 a1, float4 a2, float4 a3,
                                          float tgt, float s128, const float* lt) {
    const float A = fmaf(tgt, s128, UBIAS);
    float acc[16];
    #pragma unroll
    for (int k = 0; k < 16; ++k) acc[k] = 0.0f;
    #define COLP(val) { \
        float u = fminf(fmaxf(fmaf((val), -s128, A), 0.0f), BMAXF); \
        int bi = (int)u; \
        _Pragma("unroll") \
        for (int k = 0; k < 16; ++k) acc[k] += lt[bi + OFFK[k]]; }
    COLP(a0.x) COLP(a0.y) COLP(a0.z) COLP(a0.w)
    COLP(a1.x) COLP(a1.y) COLP(a1.z) COLP(a1.w)
    COLP(a2.x) COLP(a2.y) COLP(a2.z) COLP(a2.w)
    COLP(a3.x) COLP(a3.y) COLP(a3.z) COLP(a3.w)
    #undef COLP
    #pragma unroll
    for (int k = 0; k < 16; ++k) {
        #pragma unroll
        for (int m = 32; m; m >>= 1) acc[k] += __shfl_xor(acc[k], m, 64);
    }
    float uy = fminf(fmaxf(fmaf(tgt, -s128, A), 0.0f), BMAXF);
    int by = (int)uy;
    float p = 0.0f;
    #pragma unroll
    for (int k = 0; k < 16; ++k) p += __expf(acc[k] - lt[by + OFFK[k]]);
    return p * (1.0f / 16.0f);
}

// Diagnostic: 32x table build, amplified past the 40us fill cutoff.
__global__ __launch_bounds__(256) void k_tab32(const int* __restrict__ labels,
                                               float* __restrict__ ws) {
    const int bid = blockIdx.x, tid = threadIdx.x;
    __shared__ float lt[NT];
    const float rz = (float)(labels[bid] >> 20);   // runtime zero
    float keep = 0.0f;
    #pragma unroll 1
    for (int rep = 0; rep < 32; ++rep) {
        const float eps = rz * (float)rep;         // 0.0 at runtime, unfoldable
        for (int i = tid; i < NT; i += 256) {
            int ii = i < NTR ? i : (NTR - 1);
            lt[i] = log_ndtr_f(-9.5f + (float)ii * (1.0f / 128.0f) + eps);
        }
        __syncthreads();
        keep += lt[(tid + rep) & 2047];
        asm volatile("" :: "v"(keep) : "memory");
        __syncthreads();
    }
    if (tid == 0) ws[PART2 + bid] = keep;          // dead store, prevents DCE
}

// Real compute (R12 structure) with live phase x24 (rep 0 real, 23 dead).
__global__ __launch_bounds__(256) void k_live24(const float* __restrict__ logits,
                                                const int* __restrict__ labels,
                                                const float* __restrict__ temp,
                                                float* __restrict__ ws) {
    const int bid = blockIdx.x, tid = threadIdx.x;
    const int w = tid >> 6, l = tid & 63;
    __shared__ float lt[NT];
    __shared__ float bsum[4], bss[4], wacc[4];

    const int row0 = bid * 8 + w * 2;
    const float4* lf4 = (const float4*)logits;
    float4 v00 = lf4[(size_t)row0 * (NC / 4) + l +   0];
    float4 v01 = lf4[(size_t)row0 * (NC / 4) + l +  64];
    float4 v02 = lf4[(size_t)row0 * (NC / 4) + l + 128];
    float4 v03 = lf4[(size_t)row0 * (NC / 4) + l + 192];
    float4 v10 = lf4[(size_t)(row0 + 1) * (NC / 4) + l +   0];
    float4 v11 = lf4[(size_t)(row0 + 1) * (NC / 4) + l +  64];
    float4 v12 = lf4[(size_t)(row0 + 1) * (NC / 4) + l + 128];
    float4 v13 = lf4[(size_t)(row0 + 1) * (NC / 4) + l + 192];
    const int lab0 = labels[row0];
    const int lab1 = labels[row0 + 1];
    const float tmp0 = temp[0];
    const float rz = (float)(lab0 >> 20);          // runtime zero

    for (int i = tid; i < NT; i += 256) {
        int ii = i < NTR ? i : (NTR - 1);
        lt[i] = log_ndtr_f(-9.5f + (float)ii * (1.0f / 128.0f));
    }

    #define PICK(q0, q1, q2, q3, lab, outv) { \
        int ip = ((lab) >> 8) & 3, e = (lab) & 3, lp = ((lab) >> 2) & 63; \
        float4 sel = ip == 0 ? q0 : (ip == 1 ? q1 : (ip == 2 ? q2 : q3)); \
        float val = e == 0 ? sel.x : (e == 1 ? sel.y : (e == 2 ? sel.z : sel.w)); \
        outv = __shfl(val, lp, 64); }
    float t0, t1;
    PICK(v00, v01, v02, v03, lab0, t0)
    PICK(v10, v11, v12, v13, lab1, t1)
    #undef PICK

    float s = 0.0f, ss = 0.0f;
    int c0 = 0, c1 = 0;
    #define STAT(q, tt, cc) { \
        s += q.x + q.y + q.z + q.w; \
        ss = fmaf(q.x, q.x, fmaf(q.y, q.y, fmaf(q.z, q.z, fmaf(q.w, q.w, ss)))); \
        cc += (q.x >= tt) + (q.y >= tt) + (q.z >= tt) + (q.w >= tt); }
    STAT(v00, t0, c0) STAT(v01, t0, c0) STAT(v02, t0, c0) STAT(v03, t0, c0)
    STAT(v10, t1, c1) STAT(v11, t1, c1) STAT(v12, t1, c1) STAT(v13, t1, c1)
    #undef STAT

    #pragma unroll
    for (int m = 32; m; m >>= 1) {
        s  += __shfl_xor(s,  m, 64);
        ss += __shfl_xor(ss, m, 64);
        c0 += __shfl_xor(c0, m, 64);
        c1 += __shfl_xor(c1, m, 64);
    }
    if (l == 0) { bsum[w] = s; bss[w] = ss; }
    __syncthreads();

    float S1 = bsum[0] + bsum[1] + bsum[2] + bsum[3];
    float S2 = bss[0] + bss[1] + bss[2] + bss[3];
    const float N = (float)(8 * NC);
    float var = (S2 - S1 * S1 / N) / (N - 1.0f);
    const float s128 = 128.0f / (sqrtf(var) * tmp0);

    float wp = 0.0f;
    #pragma unroll 1
    for (int rep = 0; rep < 24; ++rep) {
        const float eps = rz * (float)rep;         // 0.0 at runtime
        float wp_i = 0.0f;
        if ((c0 - 1) < C0) wp_i += row_prob(v00, v01, v02, v03, t0 + eps, s128, lt);
        if ((c1 - 1) < C0) wp_i += row_prob(v10, v11, v12, v13, t1 + eps, s128, lt);
        if (rep == 0) wp = wp_i;
        asm volatile("" :: "v"(wp_i));
    }

    if (l == 0) wacc[w] = wp;
    __syncthreads();
    if (tid == 0) ws[PART + bid] = wacc[0] + wacc[1] + wacc[2] + wacc[3];
}

__global__ __launch_bounds__(256) void k_final(const float* __restrict__ ws,
                                               float* __restrict__ out) {
    const int tid = threadIdx.x;
    float p = ws[PART + tid] + ws[PART + 256 + tid] +
              ws[PART + 512 + tid] + ws[PART + 768 + tid];
    #pragma unroll
    for (int m = 32; m; m >>= 1) p += __shfl_xor(p, m, 64);
    __shared__ float t[4];
    if ((tid & 63) == 0) t[tid >> 6] = p;
    __syncthreads();
    if (tid == 0)
        out[0] = 1.0f - (t[0] + t[1] + t[2] + t[3]) * (1.0f / (float)NB);
}

extern "C" void kernel_launch(void* const* d_in, const int* in_sizes, int n_in,
                              void* d_out, int out_size, void* d_ws, size_t ws_size,
                              hipStream_t stream) {
    const float* logits = (const float*)d_in[0];
    const int*   labels = (const int*)d_in[1];
    const float* temp   = (const float*)d_in[2];
    float* ws  = (float*)d_ws;
    float* out = (float*)d_out;

    hipLaunchKernelGGL(k_tab32,  dim3(NBLK), dim3(256), 0, stream, labels, ws);
    hipLaunchKernelGGL(k_live24, dim3(NBLK), dim3(256), 0, stream,
                       logits, labels, temp, ws);
    hipLaunchKernelGGL(k_final,  dim3(1),    dim3(256), 0, stream, ws, out);
}

// Round 16
// 34.282 us; speedup vs baseline: 9.5755x; 9.5755x over previous
//
#include <hip/hip_runtime.h>
#include <math.h>

#define NB 8192
#define NC 1024

// transposed table: T[bi][k] = log_ndtr(x_bi + t_k), x_bi = -6 + bi/64, bi in [0,1024)
#define UB    384.5f     // 6*64 + 0.5 (rounding fold)
#define BMAX2 1023.0f
#define C0    48         // skip row if count(l_j >= l_y) - 1 >= C0

// ws layout (float/int index):
// [3] (int) finalize ticket
// [16..1039] per-block prob partials (1024)
// [2048..18431] transposed table (1024*16 floats, 64 KB)
#define TICKET 3
#define PART   16
#define TAB    2048
#define NBLK   1024

__device__ const float TK[16] = {
    -1.8627319f, -1.3180109f, -1.0099893f, -0.7764218f,
    -0.5791322f, -0.4022501f, -0.2372021f, -0.0784124f,
     0.0784124f,  0.2372021f,  0.4022501f,  0.5791322f,
     0.7764218f,  1.0099893f,  1.3180109f,  1.8627319f};

__device__ __forceinline__ float log_ndtr_f(float x) {
    float e = erfcf(-x * 0.70710678118654752f);
    if (e > 1e-37f) return __logf(0.5f * e);
    return -0.5f * x * x - 0.91893853320467274f - __logf(-x);
}

// 64 blocks: build transposed table (1 eval/thread) + reset ticket
__global__ __launch_bounds__(256) void k_tab(float* __restrict__ ws) {
    const int e = blockIdx.x * 256 + threadIdx.x;   // 0..16383
    if (e == 0) ((int*)ws)[TICKET] = 0;
    const int bi = e >> 4, k = e & 15;
    float x = -6.0f + (float)bi * (1.0f / 64.0f) + TK[k];
    ws[TAB + e] = log_ndtr_f(x);
}

// prob for one live row held in registers; table lookups via global L2
__device__ __forceinline__ float row_prob_t(float4 a0, float4 a1, float4 a2, float4 a3,
                                            float tgt, float s64,
                                            const float* __restrict__ tab, int lane) {
    const float A = fmaf(tgt, s64, UB);
    float acc[16];
    #pragma unroll
    for (int k = 0; k < 16; ++k) acc[k] = 0.0f;

    #define COLP(val) { \
        float u = fminf(fmaxf(fmaf((val), -s64, A), 0.0f), BMAX2); \
        const float4* tp = (const float4*)(tab + (((int)u) << 4)); \
        float4 q0 = tp[0], q1 = tp[1], q2 = tp[2], q3 = tp[3]; \
        acc[0] += q0.x; acc[1] += q0.y; acc[2]  += q0.z; acc[3]  += q0.w; \
        acc[4] += q1.x; acc[5] += q1.y; acc[6]  += q1.z; acc[7]  += q1.w; \
        acc[8] += q2.x; acc[9] += q2.y; acc[10] += q2.z; acc[11] += q2.w; \
        acc[12] += q3.x; acc[13] += q3.y; acc[14] += q3.z; acc[15] += q3.w; }
    COLP(a0.x) COLP(a0.y) COLP(a0.z) COLP(a0.w)
    COLP(a1.x) COLP(a1.y) COLP(a1.z) COLP(a1.w)
    COLP(a2.x) COLP(a2.y) COLP(a2.z) COLP(a2.w)
    COLP(a3.x) COLP(a3.y) COLP(a3.z) COLP(a3.w)
    #undef COLP

    #pragma unroll
    for (int k = 0; k < 16; ++k) {
        #pragma unroll
        for (int m = 32; m; m >>= 1) acc[k] += __shfl_xor(acc[k], m, 64);
    }
    float p = 0.0f;
    if (lane == 0) {
        // exact y-term cancellation: same float ops / same table row as the y column
        float uy = fminf(fmaxf(fmaf(tgt, -s64, A), 0.0f), BMAX2);
        const float4* ty4 = (const float4*)(tab + (((int)uy) << 4));
        float4 y0 = ty4[0], y1 = ty4[1], y2 = ty4[2], y3 = ty4[3];
        float ty[16] = {y0.x, y0.y, y0.z, y0.w, y1.x, y1.y, y1.z, y1.w,
                        y2.x, y2.y, y2.z, y2.w, y3.x, y3.y, y3.z, y3.w};
        #pragma unroll
        for (int k = 0; k < 16; ++k) p += __expf(acc[k] - ty[k]);
    }
    return p * (1.0f / 16.0f);
}

__global__ __launch_bounds__(256) void k_mega(const float* __restrict__ logits,
                                              const int* __restrict__ labels,
                                              const float* __restrict__ temp,
                                              float* __restrict__ ws,
                                              float* __restrict__ out) {
    const int bid = blockIdx.x, tid = threadIdx.x;
    const int w = tid >> 6, l = tid & 63;
    int* wsi = (int*)ws;

    __shared__ float bsum[4], bss[4], wacc[4];
    __shared__ int   shLast;

    const int row0 = bid * 8 + w * 2;
    const float4* lf4 = (const float4*)logits;

    // stream both rows into registers (coalesced, 128 B/lane)
    float4 v00 = lf4[(size_t)row0 * (NC / 4) + l +   0];
    float4 v01 = lf4[(size_t)row0 * (NC / 4) + l +  64];
    float4 v02 = lf4[(size_t)row0 * (NC / 4) + l + 128];
    float4 v03 = lf4[(size_t)row0 * (NC / 4) + l + 192];
    float4 v10 = lf4[(size_t)(row0 + 1) * (NC / 4) + l +   0];
    float4 v11 = lf4[(size_t)(row0 + 1) * (NC / 4) + l +  64];
    float4 v12 = lf4[(size_t)(row0 + 1) * (NC / 4) + l + 128];
    float4 v13 = lf4[(size_t)(row0 + 1) * (NC / 4) + l + 192];
    const int lab0 = labels[row0];
    const int lab1 = labels[row0 + 1];
    const float tmp0 = temp[0];

    // tgt via in-register select + shfl
    #define PICK(q0, q1, q2, q3, lab, outv) { \
        int ip = ((lab) >> 8) & 3, e = (lab) & 3, lp = ((lab) >> 2) & 63; \
        float4 sel = ip == 0 ? q0 : (ip == 1 ? q1 : (ip == 2 ? q2 : q3)); \
        float val = e == 0 ? sel.x : (e == 1 ? sel.y : (e == 2 ? sel.z : sel.w)); \
        outv = __shfl(val, lp, 64); }
    float t0, t1;
    PICK(v00, v01, v02, v03, lab0, t0)
    PICK(v10, v11, v12, v13, lab1, t1)
    #undef PICK

    // stats + counts from registers
    float s = 0.0f, ss = 0.0f;
    int c0 = 0, c1 = 0;
    #define STAT(q, tt, cc) { \
        s += q.x + q.y + q.z + q.w; \
        ss = fmaf(q.x, q.x, fmaf(q.y, q.y, fmaf(q.z, q.z, fmaf(q.w, q.w, ss)))); \
        cc += (q.x >= tt) + (q.y >= tt) + (q.z >= tt) + (q.w >= tt); }
    STAT(v00, t0, c0) STAT(v01, t0, c0) STAT(v02, t0, c0) STAT(v03, t0, c0)
    STAT(v10, t1, c1) STAT(v11, t1, c1) STAT(v12, t1, c1) STAT(v13, t1, c1)
    #undef STAT

    #pragma unroll
    for (int m = 32; m; m >>= 1) {
        s  += __shfl_xor(s,  m, 64);
        ss += __shfl_xor(ss, m, 64);
        c0 += __shfl_xor(c0, m, 64);
        c1 += __shfl_xor(c1, m, 64);
    }
    if (l == 0) { bsum[w] = s; bss[w] = ss; }
    __syncthreads();

    // per-block sigma (8192 samples, ~1e-4 effect on output; validated R12)
    float S1 = bsum[0] + bsum[1] + bsum[2] + bsum[3];
    float S2 = bss[0] + bss[1] + bss[2] + bss[3];
    const float N = (float)(8 * NC);
    float var = (S2 - S1 * S1 / N) / (N - 1.0f);
    const float s64 = 64.0f / (sqrtf(var) * tmp0);

    const float* tab = ws + TAB;
    float wp = 0.0f;
    if ((c0 - 1) < C0) wp += row_prob_t(v00, v01, v02, v03, t0, s64, tab, l);
    if ((c1 - 1) < C0) wp += row_prob_t(v10, v11, v12, v13, t1, s64, tab, l);

    if (l == 0) wacc[w] = wp;
    __syncthreads();

    // fused finalize: 1024-block ticket (R8-proven pattern), fixed-order reduce
    if (tid == 0) {
        float part = wacc[0] + wacc[1] + wacc[2] + wacc[3];
        __hip_atomic_store(&ws[PART + bid], part, __ATOMIC_RELAXED,
                           __HIP_MEMORY_SCOPE_AGENT);
        int t = __hip_atomic_fetch_add(wsi + TICKET, 1, __ATOMIC_ACQ_REL,
                                       __HIP_MEMORY_SCOPE_AGENT);
        shLast = (t == NBLK - 1);
    }
    __syncthreads();
    if (shLast) {
        float p = 0.0f;
        #pragma unroll
        for (int j = 0; j < 4; ++j)
            p += __hip_atomic_load(&ws[PART + tid + j * 256], __ATOMIC_RELAXED,
                                   __HIP_MEMORY_SCOPE_AGENT);
        #pragma unroll
        for (int m = 32; m; m >>= 1) p += __shfl_xor(p, m, 64);
        if (l == 0) wacc[w] = p;
        __syncthreads();
        if (tid == 0)
            out[0] = 1.0f - (wacc[0] + wacc[1] + wacc[2] + wacc[3]) * (1.0f / (float)NB);
    }
}

extern "C" void kernel_launch(void* const* d_in, const int* in_sizes, int n_in,
                              void* d_out, int out_size, void* d_ws, size_t ws_size,
                              hipStream_t stream) {
    const float* logits = (const float*)d_in[0];
    const int*   labels = (const int*)d_in[1];
    const float* temp   = (const float*)d_in[2];
    float* ws  = (float*)d_ws;
    float* out = (float*)d_out;

    hipLaunchKernelGGL(k_tab,  dim3(64),   dim3(256), 0, stream, ws);
    hipLaunchKernelGGL(k_mega, dim3(NBLK), dim3(256), 0, stream,
                       logits, labels, temp, ws, out);
}

// Round 17
// 30.576 us; speedup vs baseline: 10.7362x; 1.1212x over previous
//
#include <hip/hip_runtime.h>
#include <math.h>

#define NB 8192
#define NC 1024

// transposed LDS table: T[bi][k] = log_ndtr(x_bi + t_k), x_bi = -6 + bi/32,
// bi in [0,384). Quad-swizzled: quad q of row bi stored at quad (q ^ (bi&3)).
#define NBI   384
#define UB    192.5f     // 6*32 + 0.5 (rounding fold)
#define BMAX2 383.0f
#define C0    48         // skip row if count(l_j >= l_y) - 1 >= C0

// ws layout (float/int index):
// [3] (int) finalize ticket
// [16..1039] per-block prob partials (1024)
// [2048..8191] swizzled transposed table (384*16 floats, 24 KB)
#define TICKET 3
#define PART   16
#define TAB    2048
#define NTF    (NBI * 16)
#define NBLK   1024

__device__ const float TK[16] = {
    -1.8627319f, -1.3180109f, -1.0099893f, -0.7764218f,
    -0.5791322f, -0.4022501f, -0.2372021f, -0.0784124f,
     0.0784124f,  0.2372021f,  0.4022501f,  0.5791322f,
     0.7764218f,  1.0099893f,  1.3180109f,  1.8627319f};

__device__ __forceinline__ float log_ndtr_f(float x) {
    float e = erfcf(-x * 0.70710678118654752f);
    if (e > 1e-37f) return __logf(0.5f * e);
    return -0.5f * x * x - 0.91893853320467274f - __logf(-x);
}

// 24 blocks: build swizzled transposed table (1 eval/thread) + reset ticket
__global__ __launch_bounds__(256) void k_tab(float* __restrict__ ws) {
    const int e = blockIdx.x * 256 + threadIdx.x;   // 0..6143
    if (e == 0) ((int*)ws)[TICKET] = 0;
    const int bi = e >> 4, k = e & 15;
    const int q = k >> 2, sw = bi & 3;
    float x = -6.0f + (float)bi * (1.0f / 32.0f) + TK[k];
    ws[TAB + bi * 16 + ((q ^ sw) << 2) + (k & 3)] = log_ndtr_f(x);
}

// prob for one live row held in registers; 4 x ds_read_b128 per column
__device__ __forceinline__ float row_prob_t(float4 a0, float4 a1, float4 a2, float4 a3,
                                            float tgt, float s32,
                                            const float* __restrict__ lt, int lane) {
    const float A = fmaf(tgt, s32, UB);
    float acc[16];
    #pragma unroll
    for (int k = 0; k < 16; ++k) acc[k] = 0.0f;

    #define COLP(val) { \
        float u = fminf(fmaxf(fmaf((val), -s32, A), 0.0f), BMAX2); \
        int bi = (int)u, sw = bi & 3; \
        const float4* tp = (const float4*)(lt + (bi << 4)); \
        float4 q0 = tp[sw], q1 = tp[sw ^ 1], q2 = tp[sw ^ 2], q3 = tp[sw ^ 3]; \
        acc[0]  += q0.x; acc[1]  += q0.y; acc[2]  += q0.z; acc[3]  += q0.w; \
        acc[4]  += q1.x; acc[5]  += q1.y; acc[6]  += q1.z; acc[7]  += q1.w; \
        acc[8]  += q2.x; acc[9]  += q2.y; acc[10] += q2.z; acc[11] += q2.w; \
        acc[12] += q3.x; acc[13] += q3.y; acc[14] += q3.z; acc[15] += q3.w; }
    COLP(a0.x) COLP(a0.y) COLP(a0.z) COLP(a0.w)
    COLP(a1.x) COLP(a1.y) COLP(a1.z) COLP(a1.w)
    COLP(a2.x) COLP(a2.y) COLP(a2.z) COLP(a2.w)
    COLP(a3.x) COLP(a3.y) COLP(a3.z) COLP(a3.w)
    #undef COLP

    #pragma unroll
    for (int k = 0; k < 16; ++k) {
        #pragma unroll
        for (int m = 32; m; m >>= 1) acc[k] += __shfl_xor(acc[k], m, 64);
    }
    float p = 0.0f;
    if (lane == 0) {
        // exact y-term cancellation: identical float ops / same table row
        float uy = fminf(fmaxf(fmaf(tgt, -s32, A), 0.0f), BMAX2);
        int bi = (int)uy, sw = bi & 3;
        const float4* tp = (const float4*)(lt + (bi << 4));
        float4 y0 = tp[sw], y1 = tp[sw ^ 1], y2 = tp[sw ^ 2], y3 = tp[sw ^ 3];
        float ty[16] = {y0.x, y0.y, y0.z, y0.w, y1.x, y1.y, y1.z, y1.w,
                        y2.x, y2.y, y2.z, y2.w, y3.x, y3.y, y3.z, y3.w};
        #pragma unroll
        for (int k = 0; k < 16; ++k) p += __expf(acc[k] - ty[k]);
    }
    return p * (1.0f / 16.0f);
}

__global__ __launch_bounds__(256) void k_mega(const float* __restrict__ logits,
                                              const int* __restrict__ labels,
                                              const float* __restrict__ temp,
                                              float* __restrict__ ws,
                                              float* __restrict__ out) {
    const int bid = blockIdx.x, tid = threadIdx.x;
    const int w = tid >> 6, l = tid & 63;
    int* wsi = (int*)ws;

    __shared__ float lt[NTF];
    __shared__ float bsum[4], bss[4], wacc[4];
    __shared__ int   shLast;

    const int row0 = bid * 8 + w * 2;
    const float4* lf4 = (const float4*)logits;

    // stream both rows into registers (coalesced, 128 B/lane)
    float4 v00 = lf4[(size_t)row0 * (NC / 4) + l +   0];
    float4 v01 = lf4[(size_t)row0 * (NC / 4) + l +  64];
    float4 v02 = lf4[(size_t)row0 * (NC / 4) + l + 128];
    float4 v03 = lf4[(size_t)row0 * (NC / 4) + l + 192];
    float4 v10 = lf4[(size_t)(row0 + 1) * (NC / 4) + l +   0];
    float4 v11 = lf4[(size_t)(row0 + 1) * (NC / 4) + l +  64];
    float4 v12 = lf4[(size_t)(row0 + 1) * (NC / 4) + l + 128];
    float4 v13 = lf4[(size_t)(row0 + 1) * (NC / 4) + l + 192];
    const int lab0 = labels[row0];
    const int lab1 = labels[row0 + 1];
    const float tmp0 = temp[0];

    // cooperative table copy from L2 (6 float4 / thread, no VALU build)
    {
        float4* lt4 = (float4*)lt;
        const float4* gt4 = (const float4*)(ws + TAB);
        #pragma unroll
        for (int j = 0; j < NTF / 4 / 256; ++j)
            lt4[tid + j * 256] = gt4[tid + j * 256];
    }

    // tgt via in-register select + shfl
    #define PICK(q0, q1, q2, q3, lab, outv) { \
        int ip = ((lab) >> 8) & 3, e = (lab) & 3, lp = ((lab) >> 2) & 63; \
        float4 sel = ip == 0 ? q0 : (ip == 1 ? q1 : (ip == 2 ? q2 : q3)); \
        float val = e == 0 ? sel.x : (e == 1 ? sel.y : (e == 2 ? sel.z : sel.w)); \
        outv = __shfl(val, lp, 64); }
    float t0, t1;
    PICK(v00, v01, v02, v03, lab0, t0)
    PICK(v10, v11, v12, v13, lab1, t1)
    #undef PICK

    // stats + counts from registers
    float s = 0.0f, ss = 0.0f;
    int c0 = 0, c1 = 0;
    #define STAT(q, tt, cc) { \
        s += q.x + q.y + q.z + q.w; \
        ss = fmaf(q.x, q.x, fmaf(q.y, q.y, fmaf(q.z, q.z, fmaf(q.w, q.w, ss)))); \
        cc += (q.x >= tt) + (q.y >= tt) + (q.z >= tt) + (q.w >= tt); }
    STAT(v00, t0, c0) STAT(v01, t0, c0) STAT(v02, t0, c0) STAT(v03, t0, c0)
    STAT(v10, t1, c1) STAT(v11, t1, c1) STAT(v12, t1, c1) STAT(v13, t1, c1)
    #undef STAT

    #pragma unroll
    for (int m = 32; m; m >>= 1) {
        s  += __shfl_xor(s,  m, 64);
        ss += __shfl_xor(ss, m, 64);
        c0 += __shfl_xor(c0, m, 64);
        c1 += __shfl_xor(c1, m, 64);
    }
    if (l == 0) { bsum[w] = s; bss[w] = ss; }
    __syncthreads();   // covers table copy + stats

    // per-block sigma (8192 samples, ~1e-4 output effect; validated R12)
    float S1 = bsum[0] + bsum[1] + bsum[2] + bsum[3];
    float S2 = bss[0] + bss[1] + bss[2] + bss[3];
    const float N = (float)(8 * NC);
    float var = (S2 - S1 * S1 / N) / (N - 1.0f);
    const float s32 = 32.0f / (sqrtf(var) * tmp0);

    float wp = 0.0f;
    if ((c0 - 1) < C0) wp += row_prob_t(v00, v01, v02, v03, t0, s32, lt, l);
    if ((c1 - 1) < C0) wp += row_prob_t(v10, v11, v12, v13, t1, s32, lt, l);

    if (l == 0) wacc[w] = wp;
    __syncthreads();

    // fused finalize: 1024-block ticket (R8-proven), fixed-order reduce
    if (tid == 0) {
        float part = wacc[0] + wacc[1] + wacc[2] + wacc[3];
        __hip_atomic_store(&ws[PART + bid], part, __ATOMIC_RELAXED,
                           __HIP_MEMORY_SCOPE_AGENT);
        int t = __hip_atomic_fetch_add(wsi + TICKET, 1, __ATOMIC_ACQ_REL,
                                       __HIP_MEMORY_SCOPE_AGENT);
        shLast = (t == NBLK - 1);
    }
    __syncthreads();
    if (shLast) {
        float p = 0.0f;
        #pragma unroll
        for (int j = 0; j < 4; ++j)
            p += __hip_atomic_load(&ws[PART + tid + j * 256], __ATOMIC_RELAXED,
                                   __HIP_MEMORY_SCOPE_AGENT);
        #pragma unroll
        for (int m = 32; m; m >>= 1) p += __shfl_xor(p, m, 64);
        if (l == 0) wacc[w] = p;
        __syncthreads();
        if (tid == 0)
            out[0] = 1.0f - (wacc[0] + wacc[1] + wacc[2] + wacc[3]) * (1.0f / (float)NB);
    }
}

extern "C" void kernel_launch(void* const* d_in, const int* in_sizes, int n_in,
                              void* d_out, int out_size, void* d_ws, size_t ws_size,
                              hipStream_t stream) {
    const float* logits = (const float*)d_in[0];
    const int*   labels = (const int*)d_in[1];
    const float* temp   = (const float*)d_in[2];
    float* ws  = (float*)d_ws;
    float* out = (float*)d_out;

    hipLaunchKernelGGL(k_tab,  dim3(NTF / 256), dim3(256), 0, stream, ws);
    hipLaunchKernelGGL(k_mega, dim3(NBLK),      dim3(256), 0, stream,
                       logits, labels, temp, ws, out);
}